// Round 3
// baseline (116.040 us; speedup 1.0000x reference)
//
#include <hip/hip_runtime.h>
#include <hip/hip_bf16.h>
#include <math.h>

#define N_NODE 10
#define N_FEAT 8
#define HID 80
#define IN_DIM 40

typedef __attribute__((ext_vector_type(8))) short bf16x8;
typedef __attribute__((ext_vector_type(4))) float f32x4;

// Hardware RNE convert; compiler pairs these into v_cvt_pk_bf16_f32.
__device__ __forceinline__ short f2bf(float f) {
    return (short)__builtin_bit_cast(unsigned short, __float2bfloat16(f));
}

// ---------------------------------------------------------------------------
// Fold GraphConv (fixed circulant adjacency) + W_rel/W_root + decoder into
// W_mid [HID][IN_DIM], b_mid [IN_DIM]:  out = relu(relu(x@W_enc+b_enc)@W_mid+b_mid)
// ---------------------------------------------------------------------------
__global__ void precompute_kernel(const float* __restrict__ W_rel,
                                  const float* __restrict__ b_rel,
                                  const float* __restrict__ W_root,
                                  const float* __restrict__ W_dec,
                                  const float* __restrict__ b_dec,
                                  float* __restrict__ W_mid,
                                  float* __restrict__ b_mid)
{
    const float w = expf(-1.0f / 9.0f);
    const int idx = blockIdx.x * blockDim.x + threadIdx.x;
    const int nthr = gridDim.x * blockDim.x;

    for (int e = idx; e < HID * IN_DIM; e += nthr) {
        const int o  = e % IN_DIM;
        const int sf = e / IN_DIM;
        const int s  = sf / N_FEAT;
        const int f  = sf % N_FEAT;
        const int sp = (s + 1) % N_NODE;
        const int sm = (s + N_NODE - 1) % N_NODE;
        float acc = 0.0f;
        #pragma unroll
        for (int g = 0; g < N_FEAT; ++g) {
            acc = fmaf(W_root[f * N_FEAT + g], W_dec[(s  * N_FEAT + g) * IN_DIM + o], acc);
            acc = fmaf(w * W_rel[f * N_FEAT + g],
                       W_dec[(sp * N_FEAT + g) * IN_DIM + o] +
                       W_dec[(sm * N_FEAT + g) * IN_DIM + o], acc);
        }
        W_mid[e] = acc;
    }

    for (int o = idx; o < IN_DIM; o += nthr) {
        float acc = b_dec[o];
        #pragma unroll
        for (int t = 0; t < N_NODE; ++t)
            #pragma unroll
            for (int g = 0; g < N_FEAT; ++g)
                acc = fmaf(b_rel[g], W_dec[(t * N_FEAT + g) * IN_DIM + o], acc);
        b_mid[o] = acc;
    }
}

// ---------------------------------------------------------------------------
// Fully-in-register fused MLP, zero LDS.
// Layer 1 computed TRANSPOSED (y^T = W_enc^T x^T): output lane layout is
// y[m][16t+4q+r] -> each lane holds a whole y-row. Layer 2 uses the k-mapping
// f(q,e) = 32s + 16*(e>>2) + 4q + (e&3)  (bijective per 32-step, applied to
// BOTH operands -> correct for any HW k-permutation), which makes the layer-2
// A-fragment exactly the layer-1 accumulators after relu+cvt. No transpose.
// Biases ride spare k-slots (k=40 layer1, n=80 layer2) against a constant-1.0
// input slot. Next tile's x is software-prefetched (issue-early / use-late).
// ---------------------------------------------------------------------------
__global__ __launch_bounds__(256) void fused_mfma_kernel(
    const float* __restrict__ x,
    const float* __restrict__ W_enc,   // [IN_DIM][HID]
    const float* __restrict__ b_enc,   // [HID]
    const float* __restrict__ W_mid,   // [HID][IN_DIM]
    const float* __restrict__ b_mid,   // [IN_DIM]
    float* __restrict__ out,
    int B, int ntiles)
{
    const int tid  = threadIdx.x;
    const int wave = tid >> 6;
    const int lane = tid & 63;
    const int m = lane & 15;
    const int q = lane >> 4;

    // ---- static weight fragments (gathered once; weights tiny, L2-hot) ----
    // Layer-1 A-operand: W_enc^T row (16t+m), k-slot 32s+8q+e; k==40 is bias row.
    bf16x8 Wf1[5][2];
    #pragma unroll
    for (int t = 0; t < 5; ++t)
        #pragma unroll
        for (int s = 0; s < 2; ++s)
            #pragma unroll
            for (int e = 0; e < 8; ++e) {
                const int k = 32 * s + 8 * q + e;
                float v = 0.0f;
                if (k < IN_DIM)       v = W_enc[k * HID + 16 * t + m];
                else if (k == IN_DIM) v = b_enc[16 * t + m];
                Wf1[t][s][e] = f2bf(v);
            }

    // Layer-2 B-operand: W_mid[n][16t+m], n = 32s+16*(e>>2)+4q+(e&3); n==80 is bias row.
    bf16x8 Wf2[3][3];
    #pragma unroll
    for (int t = 0; t < 3; ++t) {
        const int o = 16 * t + m;
        #pragma unroll
        for (int s = 0; s < 3; ++s)
            #pragma unroll
            for (int e = 0; e < 8; ++e) {
                const int n = 32 * s + 16 * (e >> 2) + 4 * q + (e & 3);
                float v = 0.0f;
                if (o < IN_DIM) {
                    if (n < HID)       v = W_mid[n * IN_DIM + o];
                    else if (n == HID) v = b_mid[o];
                }
                Wf2[t][s][e] = f2bf(v);
            }
    }

    const int wstride = gridDim.x * 4;
    int it = blockIdx.x * 4 + wave;
    if (it >= ntiles) return;

    const float4 z4 = {0.f, 0.f, 0.f, 0.f};
    float4 c0 = z4, c1 = z4, c2 = z4, c3 = z4;
    {
        const size_t row = (size_t)it * 16 + m;
        if (row < (size_t)B) {
            const float* xr = x + row * IN_DIM;
            c0 = *(const float4*)(xr + 8 * q);
            c1 = *(const float4*)(xr + 8 * q + 4);
            if (q == 0) { c2 = *(const float4*)(xr + 32); c3 = *(const float4*)(xr + 36); }
        }
    }

    while (true) {
        const int itn = it + wstride;

        // ---- prefetch next tile (issue-early; waited on only at rotation) ----
        float4 n0 = z4, n1 = z4, n2 = z4, n3 = z4;
        if (itn < ntiles) {
            const size_t row = (size_t)itn * 16 + m;
            if (row < (size_t)B) {
                const float* xr = x + row * IN_DIM;
                n0 = *(const float4*)(xr + 8 * q);
                n1 = *(const float4*)(xr + 8 * q + 4);
                if (q == 0) { n2 = *(const float4*)(xr + 32); n3 = *(const float4*)(xr + 36); }
            }
        }

        // ---- x fragments (layer-1 B-operand): lane holds x[m][k] ----
        bf16x8 X0, X1;
        X0[0] = f2bf(c0.x); X0[1] = f2bf(c0.y); X0[2] = f2bf(c0.z); X0[3] = f2bf(c0.w);
        X0[4] = f2bf(c1.x); X0[5] = f2bf(c1.y); X0[6] = f2bf(c1.z); X0[7] = f2bf(c1.w);
        X1[0] = f2bf(c2.x); X1[1] = f2bf(c2.y); X1[2] = f2bf(c2.z); X1[3] = f2bf(c2.w);
        X1[4] = f2bf(c3.x); X1[5] = f2bf(c3.y); X1[6] = f2bf(c3.z); X1[7] = f2bf(c3.w);
        if (q == 1) X1[0] = (short)0x3F80;     // constant 1.0 at bias k-slot 40

        // ---- layer 1 (transposed): lane gets y[m][16t+4q+r] ----
        f32x4 acc1[5];
        #pragma unroll
        for (int t = 0; t < 5; ++t) { acc1[t][0]=0.f; acc1[t][1]=0.f; acc1[t][2]=0.f; acc1[t][3]=0.f; }
        #pragma unroll
        for (int t = 0; t < 5; ++t) {
            acc1[t] = __builtin_amdgcn_mfma_f32_16x16x32_bf16(Wf1[t][0], X0, acc1[t], 0, 0, 0);
            acc1[t] = __builtin_amdgcn_mfma_f32_16x16x32_bf16(Wf1[t][1], X1, acc1[t], 0, 0, 0);
        }

        // ---- relu + repack: layer-2 A-fragment IS acc1 under f(q,e) mapping ----
        bf16x8 P0, P1, P2;
        #pragma unroll
        for (int r = 0; r < 4; ++r) {
            P0[r]     = f2bf(fmaxf(acc1[0][r], 0.f));
            P0[4 + r] = f2bf(fmaxf(acc1[1][r], 0.f));
            P1[r]     = f2bf(fmaxf(acc1[2][r], 0.f));
            P1[4 + r] = f2bf(fmaxf(acc1[3][r], 0.f));
            P2[r]     = f2bf(fmaxf(acc1[4][r], 0.f));
            P2[4 + r] = 0;
        }
        if (q == 0) P2[4] = (short)0x3F80;     // constant 1.0 at bias n-slot 80

        // ---- layer 2: out[4q+r][16t+m] ----
        f32x4 acc2[3];
        #pragma unroll
        for (int t = 0; t < 3; ++t) { acc2[t][0]=0.f; acc2[t][1]=0.f; acc2[t][2]=0.f; acc2[t][3]=0.f; }
        #pragma unroll
        for (int t = 0; t < 3; ++t) {
            acc2[t] = __builtin_amdgcn_mfma_f32_16x16x32_bf16(P0, Wf2[t][0], acc2[t], 0, 0, 0);
            acc2[t] = __builtin_amdgcn_mfma_f32_16x16x32_bf16(P1, Wf2[t][1], acc2[t], 0, 0, 0);
            acc2[t] = __builtin_amdgcn_mfma_f32_16x16x32_bf16(P2, Wf2[t][2], acc2[t], 0, 0, 0);
        }

        // ---- relu + store (quarter-wave writes 16 consecutive floats) ----
        #pragma unroll
        for (int t = 0; t < 3; ++t) {
            const int o = 16 * t + m;
            if (o < IN_DIM) {
                #pragma unroll
                for (int r = 0; r < 4; ++r) {
                    const size_t row = (size_t)it * 16 + 4 * q + r;
                    if (row < (size_t)B)
                        out[row * IN_DIM + o] = fmaxf(acc2[t][r], 0.f);
                }
            }
        }

        if (itn >= ntiles) break;
        c0 = n0; c1 = n1; c2 = n2; c3 = n3;
        it = itn;
    }
}

extern "C" void kernel_launch(void* const* d_in, const int* in_sizes, int n_in,
                              void* d_out, int out_size, void* d_ws, size_t ws_size,
                              hipStream_t stream)
{
    const float* x      = (const float*)d_in[0];
    const float* W_enc  = (const float*)d_in[1];
    const float* b_enc  = (const float*)d_in[2];
    const float* W_rel  = (const float*)d_in[3];
    const float* b_rel  = (const float*)d_in[4];
    const float* W_root = (const float*)d_in[5];
    const float* W_dec  = (const float*)d_in[6];
    const float* b_dec  = (const float*)d_in[7];
    float* out = (float*)d_out;

    const int B = in_sizes[0] / IN_DIM;
    const int ntiles = (B + 15) / 16;

    float* W_mid = (float*)d_ws;                 // HID*IN_DIM floats
    float* b_mid = W_mid + HID * IN_DIM;         // IN_DIM floats

    precompute_kernel<<<13, 256, 0, stream>>>(W_rel, b_rel, W_root, W_dec, b_dec,
                                              W_mid, b_mid);

    const int grid = 2048;                       // 8192 waves, grid-stride over tiles
    fused_mfma_kernel<<<grid, 256, 0, stream>>>(x, W_enc, b_enc, W_mid, b_mid,
                                                out, B, ntiles);
}

// Round 4
// 101.925 us; speedup vs baseline: 1.1385x; 1.1385x over previous
//
#include <hip/hip_runtime.h>
#include <math.h>

#define N_NODE 10
#define N_FEAT 8
#define HID 80
#define IN_DIM 40

typedef __attribute__((ext_vector_type(8))) short bf16x8;
typedef __attribute__((ext_vector_type(4))) float f32x4;

// Manual RNE fp32->bf16 (3 VALU ops, no NaN branch; inputs are finite).
__device__ __forceinline__ short f2bf(float f) {
    unsigned u = __builtin_bit_cast(unsigned, f);
    u += 0x7fffu + ((u >> 16) & 1u);
    return (short)(u >> 16);
}

// ws layout (floats): [0,3200) W_mid | [3200,3240) b_mid | [3240,...) frags
// frags: 19 fragments x 64 lanes x 16 B  (Wf1: fid=t*2+s, 10; Wf2: fid=10+t*3+s, 9)
#define FRAG_OFF 3240

// ---------------------------------------------------------------------------
// Fold GraphConv (fixed circulant adjacency) + W_rel/W_root + decoder into
// W_mid [HID][IN_DIM], b_mid [IN_DIM]:  out = relu(relu(x@W_enc+b_enc)@W_mid+b_mid)
// ---------------------------------------------------------------------------
__global__ void precompute_kernel(const float* __restrict__ W_rel,
                                  const float* __restrict__ b_rel,
                                  const float* __restrict__ W_root,
                                  const float* __restrict__ W_dec,
                                  const float* __restrict__ b_dec,
                                  float* __restrict__ W_mid,
                                  float* __restrict__ b_mid)
{
    const float w = expf(-1.0f / 9.0f);
    const int idx = blockIdx.x * blockDim.x + threadIdx.x;
    const int nthr = gridDim.x * blockDim.x;

    for (int e = idx; e < HID * IN_DIM; e += nthr) {
        const int o  = e % IN_DIM;
        const int sf = e / IN_DIM;
        const int s  = sf / N_FEAT;
        const int f  = sf % N_FEAT;
        const int sp = (s + 1) % N_NODE;
        const int sm = (s + N_NODE - 1) % N_NODE;
        float acc = 0.0f;
        #pragma unroll
        for (int g = 0; g < N_FEAT; ++g) {
            acc = fmaf(W_root[f * N_FEAT + g], W_dec[(s  * N_FEAT + g) * IN_DIM + o], acc);
            acc = fmaf(w * W_rel[f * N_FEAT + g],
                       W_dec[(sp * N_FEAT + g) * IN_DIM + o] +
                       W_dec[(sm * N_FEAT + g) * IN_DIM + o], acc);
        }
        W_mid[e] = acc;
    }

    for (int o = idx; o < IN_DIM; o += nthr) {
        float acc = b_dec[o];
        #pragma unroll
        for (int t = 0; t < N_NODE; ++t)
            #pragma unroll
            for (int g = 0; g < N_FEAT; ++g)
                acc = fmaf(b_rel[g], W_dec[(t * N_FEAT + g) * IN_DIM + o], acc);
        b_mid[o] = acc;
    }
}

// ---------------------------------------------------------------------------
// Pack bf16 weight fragments (with biases riding spare k-slots) into ws so the
// main kernel's prologue is 19 fully-coalesced dwordx4 loads instead of 152
// uncoalesced 4B gathers per wave.
//   Wf1[t][s] lane(m,q) elem e : k=32s+8q+e       -> W_enc[k][16t+m], k==40 -> b_enc
//   Wf2[t][s] lane(m,q) elem e : n=32s+16(e>>2)+4q+(e&3) -> W_mid[n][16t+m], n==80 -> b_mid
// ---------------------------------------------------------------------------
__global__ void pack_frags_kernel(const float* __restrict__ W_enc,
                                  const float* __restrict__ b_enc,
                                  float* __restrict__ ws)
{
    const int lane = threadIdx.x;           // 64 threads
    const int m = lane & 15;
    const int q = lane >> 4;
    const float* W_mid = ws;
    const float* b_mid = ws + HID * IN_DIM;
    unsigned* fb = (unsigned*)(ws + FRAG_OFF);

    #pragma unroll
    for (int t = 0; t < 5; ++t)
        #pragma unroll
        for (int s = 0; s < 2; ++s) {
            short v[8];
            #pragma unroll
            for (int e = 0; e < 8; ++e) {
                const int k = 32 * s + 8 * q + e;
                float f = 0.0f;
                if (k < IN_DIM)       f = W_enc[k * HID + 16 * t + m];
                else if (k == IN_DIM) f = b_enc[16 * t + m];
                v[e] = f2bf(f);
            }
            const int fid = t * 2 + s;
            #pragma unroll
            for (int j = 0; j < 4; ++j)
                fb[fid * 256 + lane * 4 + j] =
                    (unsigned)(unsigned short)v[2 * j] |
                    ((unsigned)(unsigned short)v[2 * j + 1] << 16);
        }

    #pragma unroll
    for (int t = 0; t < 3; ++t) {
        const int o = 16 * t + m;
        #pragma unroll
        for (int s = 0; s < 3; ++s) {
            short v[8];
            #pragma unroll
            for (int e = 0; e < 8; ++e) {
                const int n = 32 * s + 16 * (e >> 2) + 4 * q + (e & 3);
                float f = 0.0f;
                if (o < IN_DIM) {
                    if (n < HID)       f = W_mid[n * IN_DIM + o];
                    else if (n == HID) f = b_mid[o];
                }
                v[e] = f2bf(f);
            }
            const int fid = 10 + t * 3 + s;
            #pragma unroll
            for (int j = 0; j < 4; ++j)
                fb[fid * 256 + lane * 4 + j] =
                    (unsigned)(unsigned short)v[2 * j] |
                    ((unsigned)(unsigned short)v[2 * j + 1] << 16);
        }
    }
}

// ---------------------------------------------------------------------------
// Fully-in-register fused MLP, zero LDS, both layers operand-swapped.
// Layer 1 (A=W_enc^T, B=x^T): lane(m,q) gets y[m][16t+4q+r] -> whole y-row in
// lane. Layer-2 k-mapping f(q,e)=32s+16(e>>2)+4q+(e&3) makes the layer-2
// B-fragment exactly the relu+cvt of layer-1 accumulators (no transpose).
// Layer 2 ALSO swapped (A=W_mid-frag, B=P): D gives lane(m,q) out[m][16t+4q+r]
// -> per-lane float4 stores, 3 store insts/tile. Biases ride spare k-slots.
// ---------------------------------------------------------------------------
__global__ __launch_bounds__(256) void fused_mfma_kernel(
    const float* __restrict__ x,
    const float* __restrict__ ws,      // W_mid/b_mid/frags
    float* __restrict__ out,
    int B, int ntiles)
{
    const int tid  = threadIdx.x;
    const int wave = tid >> 6;
    const int lane = tid & 63;
    const int m = lane & 15;
    const int q = lane >> 4;

    // ---- coalesced fragment prologue: 19 x dwordx4, L2-hot ----
    typedef __attribute__((ext_vector_type(4))) unsigned uint4v;
    const uint4v* fb = (const uint4v*)(ws + FRAG_OFF);
    bf16x8 Wf1[5][2];
    #pragma unroll
    for (int t = 0; t < 5; ++t)
        #pragma unroll
        for (int s = 0; s < 2; ++s)
            Wf1[t][s] = __builtin_bit_cast(bf16x8, fb[(t * 2 + s) * 64 + lane]);
    bf16x8 Wf2[3][3];
    #pragma unroll
    for (int t = 0; t < 3; ++t)
        #pragma unroll
        for (int s = 0; s < 3; ++s)
            Wf2[t][s] = __builtin_bit_cast(bf16x8, fb[(10 + t * 3 + s) * 64 + lane]);

    const int wstride = gridDim.x * 4;
    int it = blockIdx.x * 4 + wave;
    if (it >= ntiles) return;

    const float4 z4 = {0.f, 0.f, 0.f, 0.f};
    float4 c0 = z4, c1 = z4, c2 = z4, c3 = z4;
    {
        const size_t row = (size_t)it * 16 + m;
        if (row < (size_t)B) {
            const float* xr = x + row * IN_DIM;
            c0 = *(const float4*)(xr + 8 * q);
            c1 = *(const float4*)(xr + 8 * q + 4);
            if (q == 0) { c2 = *(const float4*)(xr + 32); c3 = *(const float4*)(xr + 36); }
        }
    }

    while (true) {
        const int itn = it + wstride;

        // ---- prefetch next tile (issue-early / use-late) ----
        float4 n0 = z4, n1 = z4, n2 = z4, n3 = z4;
        if (itn < ntiles) {
            const size_t row = (size_t)itn * 16 + m;
            if (row < (size_t)B) {
                const float* xr = x + row * IN_DIM;
                n0 = *(const float4*)(xr + 8 * q);
                n1 = *(const float4*)(xr + 8 * q + 4);
                if (q == 0) { n2 = *(const float4*)(xr + 32); n3 = *(const float4*)(xr + 36); }
            }
        }

        // ---- x fragments (layer-1 B-operand): lane holds x[m][k] ----
        bf16x8 X0, X1;
        X0[0] = f2bf(c0.x); X0[1] = f2bf(c0.y); X0[2] = f2bf(c0.z); X0[3] = f2bf(c0.w);
        X0[4] = f2bf(c1.x); X0[5] = f2bf(c1.y); X0[6] = f2bf(c1.z); X0[7] = f2bf(c1.w);
        X1[0] = f2bf(c2.x); X1[1] = f2bf(c2.y); X1[2] = f2bf(c2.z); X1[3] = f2bf(c2.w);
        X1[4] = f2bf(c3.x); X1[5] = f2bf(c3.y); X1[6] = f2bf(c3.z); X1[7] = f2bf(c3.w);
        if (q == 1) X1[0] = (short)0x3F80;     // 1.0 at bias k-slot 40

        // ---- layer 1 (swapped): lane gets y[m][16t+4q+r] ----
        f32x4 acc1[5];
        #pragma unroll
        for (int t = 0; t < 5; ++t) { acc1[t][0]=0.f; acc1[t][1]=0.f; acc1[t][2]=0.f; acc1[t][3]=0.f; }
        #pragma unroll
        for (int t = 0; t < 5; ++t) {
            acc1[t] = __builtin_amdgcn_mfma_f32_16x16x32_bf16(Wf1[t][0], X0, acc1[t], 0, 0, 0);
            acc1[t] = __builtin_amdgcn_mfma_f32_16x16x32_bf16(Wf1[t][1], X1, acc1[t], 0, 0, 0);
        }

        // ---- relu + repack: layer-2 B-fragment IS acc1 under f(q,e) mapping ----
        bf16x8 P0, P1, P2;
        #pragma unroll
        for (int r = 0; r < 4; ++r) {
            P0[r]     = f2bf(fmaxf(acc1[0][r], 0.f));
            P0[4 + r] = f2bf(fmaxf(acc1[1][r], 0.f));
            P1[r]     = f2bf(fmaxf(acc1[2][r], 0.f));
            P1[4 + r] = f2bf(fmaxf(acc1[3][r], 0.f));
            P2[r]     = f2bf(fmaxf(acc1[4][r], 0.f));
            P2[4 + r] = 0;
        }
        if (q == 0) P2[4] = (short)0x3F80;     // 1.0 at bias n-slot 80

        // ---- layer 2 (swapped): lane gets out[m][16t+4q+r] ----
        f32x4 acc2[3];
        #pragma unroll
        for (int t = 0; t < 3; ++t) { acc2[t][0]=0.f; acc2[t][1]=0.f; acc2[t][2]=0.f; acc2[t][3]=0.f; }
        #pragma unroll
        for (int t = 0; t < 3; ++t) {
            acc2[t] = __builtin_amdgcn_mfma_f32_16x16x32_bf16(Wf2[t][0], P0, acc2[t], 0, 0, 0);
            acc2[t] = __builtin_amdgcn_mfma_f32_16x16x32_bf16(Wf2[t][1], P1, acc2[t], 0, 0, 0);
            acc2[t] = __builtin_amdgcn_mfma_f32_16x16x32_bf16(Wf2[t][2], P2, acc2[t], 0, 0, 0);
        }

        // ---- relu + per-lane float4 stores (3 insts, 64B row-segments) ----
        {
            const size_t row = (size_t)it * 16 + m;
            if (row < (size_t)B) {
                float* orow = out + row * IN_DIM;
                #pragma unroll
                for (int t = 0; t < 3; ++t) {
                    const int o0 = 16 * t + 4 * q;
                    if (o0 < IN_DIM) {
                        float4 v;
                        v.x = fmaxf(acc2[t][0], 0.f);
                        v.y = fmaxf(acc2[t][1], 0.f);
                        v.z = fmaxf(acc2[t][2], 0.f);
                        v.w = fmaxf(acc2[t][3], 0.f);
                        *(float4*)(orow + o0) = v;
                    }
                }
            }
        }

        if (itn >= ntiles) break;
        c0 = n0; c1 = n1; c2 = n2; c3 = n3;
        it = itn;
    }
}

extern "C" void kernel_launch(void* const* d_in, const int* in_sizes, int n_in,
                              void* d_out, int out_size, void* d_ws, size_t ws_size,
                              hipStream_t stream)
{
    const float* x      = (const float*)d_in[0];
    const float* W_enc  = (const float*)d_in[1];
    const float* b_enc  = (const float*)d_in[2];
    const float* W_rel  = (const float*)d_in[3];
    const float* b_rel  = (const float*)d_in[4];
    const float* W_root = (const float*)d_in[5];
    const float* W_dec  = (const float*)d_in[6];
    const float* b_dec  = (const float*)d_in[7];
    float* out = (float*)d_out;

    const int B = in_sizes[0] / IN_DIM;
    const int ntiles = (B + 15) / 16;

    float* ws = (float*)d_ws;
    float* W_mid = ws;                       // [0, 3200)
    float* b_mid = ws + HID * IN_DIM;        // [3200, 3240)

    precompute_kernel<<<13, 256, 0, stream>>>(W_rel, b_rel, W_root, W_dec, b_dec,
                                              W_mid, b_mid);
    pack_frags_kernel<<<1, 64, 0, stream>>>(W_enc, b_enc, ws);

    const int grid = 4096;                   // 16384 waves, 4 tiles/wave
    fused_mfma_kernel<<<grid, 256, 0, stream>>>(x, ws, out, B, ntiles);
}